// Round 7
// baseline (259.048 us; speedup 1.0000x reference)
//
#include <hip/hip_runtime.h>
#include <math.h>

// Problem constants
constexpr int LQ  = 1024;   // sequence length
constexpr int NH  = 32;     // heads
constexpr int HDM = 64;     // head dim
constexpr int FDM = 64;     // feature dim
constexpr int HID = 2048;   // NH*HDM
constexpr int NCH = 16;     // chunks
constexpr int CT  = 64;     // chunk length (NCH*CT == LQ)
#define EPSV 1e-12f

typedef __bf16 bf16x8 __attribute__((ext_vector_type(8)));
typedef float  f32x4  __attribute__((ext_vector_type(4)));

// fp32 -> bf16 raw bits, round-to-nearest-even
__device__ __forceinline__ unsigned short f2b_raw(float x) {
    union { float f; unsigned int u; } v; v.f = x;
    unsigned int r = v.u + 0x7fffu + ((v.u >> 16) & 1u);
    return (unsigned short)(r >> 16);
}
__device__ __forceinline__ float b2f(ushort u) {
    union { unsigned int i; float f; } v; v.i = ((unsigned int)u) << 16; return v.f;
}

// async global->LDS, 16B per lane; lds dst = wave-uniform base + lane*16
#define ASYNC16(ldsp, gp) __builtin_amdgcn_global_load_lds( \
    (const __attribute__((address_space(1))) void*)(gp),    \
    (__attribute__((address_space(3))) void*)(ldsp), 16, 0, 0)

// ---------------------------------------------------------------------------
// Generic bf16 MFMA GEMM core (NT), BK=64, double-buffered, XOR-swizzled LDS.
// Used by gemm_one (64x128).
// ---------------------------------------------------------------------------
template <int TM, int TN, bool BF16OUT>
__device__ __forceinline__ void gemm_core(const ushort* __restrict__ A,
                                          const ushort* __restrict__ B,
                                          void* __restrict__ Cv,
                                          int M, int N, int K) {
    constexpr int FI = TM / 32, FJ = TN / 32;
    constexpr int AI = TM / 32, BJ = TN / 32;
    constexpr int ASZ = TM * 64, BSZ = TN * 64;
    __shared__ __align__(16) ushort As[2 * ASZ];
    __shared__ __align__(16) ushort Bs[2 * BSZ];

    const int t = threadIdx.x, wave = t >> 6, lane = t & 63;
    const int wr = (wave >> 1) * (TM / 2), wc = (wave & 1) * (TN / 2);
    const int bm = blockIdx.y * TM, bn = blockIdx.x * TN;

    const int grow = lane >> 3;
    const int gsw  = ((lane & 7) ^ (grow & 7)) << 3;
    const int arow0 = wave * (TM / 4), brow0 = wave * (TN / 4);
    const ushort* gA = A + (size_t)(bm + arow0 + grow) * K + gsw;
    const ushort* gB = B + (size_t)(bn + brow0 + grow) * K + gsw;

    const int fr = lane & 15, q = lane >> 4;

    f32x4 acc[FI][FJ] = {};
    const int NIT = K >> 6;

    {
        ushort* ab = As + arow0 * 64;
        ushort* bb = Bs + brow0 * 64;
#pragma unroll
        for (int i = 0; i < AI; ++i) ASYNC16(ab + i * 512, gA + (size_t)i * 8 * K);
#pragma unroll
        for (int j = 0; j < BJ; ++j) ASYNC16(bb + j * 512, gB + (size_t)j * 8 * K);
    }
    __syncthreads();

    for (int it = 0; it < NIT; ++it) {
        const int p = it & 1;
        if (it + 1 < NIT) {
            const int ko = (it + 1) << 6;
            ushort* ab = As + (p ^ 1) * ASZ + arow0 * 64;
            ushort* bb = Bs + (p ^ 1) * BSZ + brow0 * 64;
#pragma unroll
            for (int i = 0; i < AI; ++i) ASYNC16(ab + i * 512, gA + ko + (size_t)i * 8 * K);
#pragma unroll
            for (int j = 0; j < BJ; ++j) ASYNC16(bb + j * 512, gB + ko + (size_t)j * 8 * K);
        }
        const ushort* ap = As + p * ASZ;
        const ushort* bp = Bs + p * BSZ;
        bf16x8 af[2][FI], bg[2][FJ];
#pragma unroll
        for (int ks = 0; ks < 2; ++ks) {
#pragma unroll
            for (int i = 0; i < FI; ++i) {
                const int row = wr + i * 16 + fr;
                af[ks][i] = *(const bf16x8*)&ap[row * 64 + (((q + ks * 4) ^ (row & 7)) << 3)];
            }
#pragma unroll
            for (int j = 0; j < FJ; ++j) {
                const int row = wc + j * 16 + fr;
                bg[ks][j] = *(const bf16x8*)&bp[row * 64 + (((q + ks * 4) ^ (row & 7)) << 3)];
            }
        }
#pragma unroll
        for (int ks = 0; ks < 2; ++ks)
#pragma unroll
            for (int i = 0; i < FI; ++i)
#pragma unroll
                for (int j = 0; j < FJ; ++j)
                    acc[i][j] = __builtin_amdgcn_mfma_f32_16x16x32_bf16(af[ks][i], bg[ks][j], acc[i][j], 0, 0, 0);
        if (it + 1 < NIT) __syncthreads();
    }

    const int er = q * 4, ec = lane & 15;
#pragma unroll
    for (int i = 0; i < FI; ++i)
#pragma unroll
        for (int j = 0; j < FJ; ++j) {
            const size_t base = (size_t)(bm + wr + i * 16 + er) * N + bn + wc + j * 16 + ec;
            if constexpr (BF16OUT) {
                ushort* C = (ushort*)Cv;
#pragma unroll
                for (int r = 0; r < 4; ++r) C[base + (size_t)r * N] = f2b_raw(acc[i][j][r]);
            } else {
                float* C = (float*)Cv;
#pragma unroll
                for (int r = 0; r < 4; ++r) C[base + (size_t)r * N] = acc[i][j][r];
            }
        }
}

__global__ __launch_bounds__(256) void gemm_one(const ushort* __restrict__ A,
                                                const ushort* __restrict__ B,
                                                float* __restrict__ C) {
    gemm_core<64, 128, false>(A, B, C, LQ, HID, HID);
}

// ---------------------------------------------------------------------------
// Fused QKV projection + feature map (z=0: Q->fqB, z=1: K->fkB) or
// transposed V store (z=2: ->VTb [h][c][d][l]).
// m97-style 128x128 tile, BK=64, single-buffered 32KB LDS (3 blk/CU),
// 32 MFMAs per barrier pair. FM epilogue: two passes (one per head) reusing
// the GEMM LDS (Qt[128][72] + Wfs[64][72]).
// ---------------------------------------------------------------------------
__global__ __launch_bounds__(256) void gemm_qkv_fm(
    const ushort* __restrict__ hsb,
    const ushort* __restrict__ wqb, const ushort* __restrict__ wkb,
    const ushort* __restrict__ wvb,
    const ushort* __restrict__ WfqT, const ushort* __restrict__ WfkT,
    ushort* __restrict__ fqB, ushort* __restrict__ fkB,
    ushort* __restrict__ VTb) {
    __shared__ __align__(16) ushort lds[16384];   // 32 KB
    ushort* As = lds;              // [128][64]
    ushort* Bs = lds + 8192;       // [128][64]

    const int z = blockIdx.z;
    const ushort* Bmat = (z == 0) ? wqb : (z == 1) ? wkb : wvb;

    const int t = threadIdx.x, wave = t >> 6, lane = t & 63;
    const int wr = (wave >> 1) * 64, wc = (wave & 1) * 64;
    const int bx = blockIdx.x, by = blockIdx.y;
    const int bm = by * 128, bn = bx * 128;

    const int grow = lane >> 3;
    const int gsw  = ((lane & 7) ^ (grow & 7)) << 3;
    const ushort* gA = hsb  + (size_t)(bm + wave * 32 + grow) * HID + gsw;
    const ushort* gB = Bmat + (size_t)(bn + wave * 32 + grow) * HID + gsw;
    ushort* la = As + (wave * 32) * 64;
    ushort* lb = Bs + (wave * 32) * 64;

    const int fr = lane & 15, q = lane >> 4, ec = lane & 15;

    f32x4 acc[4][4] = {};

    for (int k0 = 0; k0 < HID; k0 += 64) {
        __syncthreads();                 // previous compute's LDS reads done
#pragma unroll
        for (int i = 0; i < 4; ++i) ASYNC16(la + i * 512, gA + k0 + (size_t)i * 8 * HID);
#pragma unroll
        for (int j = 0; j < 4; ++j) ASYNC16(lb + j * 512, gB + k0 + (size_t)j * 8 * HID);
        __syncthreads();                 // loads visible
        bf16x8 af[2][4], bg[2][4];
#pragma unroll
        for (int ks = 0; ks < 2; ++ks) {
#pragma unroll
            for (int i = 0; i < 4; ++i) {
                const int row = wr + i * 16 + fr;
                af[ks][i] = *(const bf16x8*)&As[row * 64 + (((q + ks * 4) ^ (row & 7)) << 3)];
            }
#pragma unroll
            for (int j = 0; j < 4; ++j) {
                const int row = wc + j * 16 + fr;
                bg[ks][j] = *(const bf16x8*)&Bs[row * 64 + (((q + ks * 4) ^ (row & 7)) << 3)];
            }
        }
#pragma unroll
        for (int ks = 0; ks < 2; ++ks)
#pragma unroll
            for (int i = 0; i < 4; ++i)
#pragma unroll
                for (int j = 0; j < 4; ++j)
                    acc[i][j] = __builtin_amdgcn_mfma_f32_16x16x32_bf16(af[ks][i], bg[ks][j], acc[i][j], 0, 0, 0);
    }

    if (z == 2) {
        // transposed V store: VTb[((head*NCH + chunk)*64 + d)*64 + l]
#pragma unroll
        for (int i = 0; i < 4; ++i)
#pragma unroll
            for (int j = 0; j < 4; ++j) {
                const int colL = wc + j * 16 + ec;          // 0..127
                const int head = 2 * bx + (colL >> 6), d = colL & 63;
                const int chunk = 2 * by + (wr >> 6);
                const int lloc = i * 16 + q * 4;            // +r contiguous
                const size_t base = (((size_t)head * NCH + chunk) * 64 + d) * 64 + lloc;
                ushort4 o = make_ushort4(f2b_raw(acc[i][j][0]), f2b_raw(acc[i][j][1]),
                                         f2b_raw(acc[i][j][2]), f2b_raw(acc[i][j][3]));
                *(ushort4*)&VTb[base] = o;
            }
        return;
    }

    // ---- fused feature map: two passes, one per head in this N-tile ----
    ushort* Qt  = lds;          // [128][72] = 9216 ushorts
    ushort* Wfs = lds + 9728;   // [64][72]  = 4608 ushorts (fits in 16384)
    ushort* outp = (z == 0) ? fqB : fkB;

    for (int hp = 0; hp < 2; ++hp) {
        __syncthreads();        // prior reads of lds done
        if ((wave & 1) == hp) { // waves holding this head's projection tile
#pragma unroll
            for (int i = 0; i < 4; ++i)
#pragma unroll
                for (int j = 0; j < 4; ++j)
#pragma unroll
                    for (int r = 0; r < 4; ++r)
                        Qt[(wr + i * 16 + q * 4 + r) * 72 + j * 16 + ec] = f2b_raw(acc[i][j][r]);
        }
        const int hgl = 2 * bx + hp;
        {
            const ushort* WT = ((z == 0) ? WfqT : WfkT) + (size_t)hgl * 4096;
            const int e = t * 16, f = e >> 6, dc = e & 63;
            *(uint4*)&Wfs[f * 72 + dc]     = *(const uint4*)&WT[e];
            *(uint4*)&Wfs[f * 72 + dc + 8] = *(const uint4*)&WT[e + 8];
        }
        __syncthreads();

        // Z = Qt @ Wfs^T : wave covers rows R0..R0+31 (all 128 rows covered)
        const int R0 = wave * 32;
        f32x4 zf[2][4] = {};
#pragma unroll
        for (int ks = 0; ks < 2; ++ks) {
            bf16x8 a[2];
#pragma unroll
            for (int i = 0; i < 2; ++i)
                a[i] = *(const bf16x8*)&Qt[(R0 + i * 16 + fr) * 72 + ks * 32 + q * 8];
#pragma unroll
            for (int j = 0; j < 4; ++j) {
                bf16x8 b = *(const bf16x8*)&Wfs[(j * 16 + fr) * 72 + ks * 32 + q * 8];
#pragma unroll
                for (int i = 0; i < 2; ++i)
                    zf[i][j] = __builtin_amdgcn_mfma_f32_16x16x32_bf16(a[i], b, zf[i][j], 0, 0, 0);
            }
        }
        // softmax over f per row, in registers (16-lane quad groups)
#pragma unroll
        for (int i = 0; i < 2; ++i)
#pragma unroll
            for (int r = 0; r < 4; ++r) {
                float m = zf[i][0][r];
#pragma unroll
                for (int j = 1; j < 4; ++j) m = fmaxf(m, zf[i][j][r]);
                m = fmaxf(m, __shfl_xor(m, 1)); m = fmaxf(m, __shfl_xor(m, 2));
                m = fmaxf(m, __shfl_xor(m, 4)); m = fmaxf(m, __shfl_xor(m, 8));
                float e4[4], s = 0.f;
#pragma unroll
                for (int j = 0; j < 4; ++j) { e4[j] = __expf(zf[i][j][r] - m); s += e4[j]; }
                s += __shfl_xor(s, 1); s += __shfl_xor(s, 2);
                s += __shfl_xor(s, 4); s += __shfl_xor(s, 8);
                const float inv = 1.0f / s;
                const int l = bm + R0 + i * 16 + q * 4 + r;
                ushort* op = outp + ((size_t)hgl * LQ + l) * FDM;
#pragma unroll
                for (int j = 0; j < 4; ++j) op[j * 16 + ec] = f2b_raw(e4[j] * inv);
            }
    }
}

// ---------------------------------------------------------------------------
// Convert: y=0..4 fp32->bf16 tensors; y=5,6 Wf transpose (h = blockIdx.x < 32)
// ---------------------------------------------------------------------------
struct ConvArgs {
    const float* src[5]; ushort* dst[5]; int n[5];
    const float* Wfq; const float* Wfk; ushort* WfqT; ushort* WfkT;
};
__global__ __launch_bounds__(256) void conv_all(ConvArgs p) {
    const int y = blockIdx.y, t = threadIdx.x;
    if (y < 5) {
        const int i = (blockIdx.x * 256 + t) * 4;
        if (i >= p.n[y]) return;
        float4 v = *(const float4*)&p.src[y][i];
        ushort4 o = make_ushort4(f2b_raw(v.x), f2b_raw(v.y), f2b_raw(v.z), f2b_raw(v.w));
        *(ushort4*)&p.dst[y][i] = o;
        return;
    }
    if (blockIdx.x >= NH) return;
    const int h = blockIdx.x;
    const float* src = ((y == 6) ? p.Wfk : p.Wfq) + (size_t)h * 4096;  // [d][f]
    ushort* dst = ((y == 6) ? p.WfkT : p.WfqT) + (size_t)h * 4096;     // [f][d]
    __shared__ float tile[64][65];
    for (int it = 0; it < 16; ++it) {
        int e = it * 256 + t; int d = e >> 6, f = e & 63;
        tile[d][f] = src[e];
    }
    __syncthreads();
    for (int it = 0; it < 16; ++it) {
        int e = it * 256 + t; int f = e >> 6, d = e & 63;
        dst[e] = f2b_raw(tile[d][f]);
    }
}

// ---------------------------------------------------------------------------
// Fused chunk-state + exclusive prefix scan (replaces chunk_state+prefix2).
// grid (NH, 8), block 256. Block (h,eb) owns d-rows eb*8..eb*8+8 of the
// [d][f] state; per chunk: stage fk-chunk + VT-rows to LDS, write the
// register-resident running prefix (bf16) then accumulate. eb==0 also scans Ks.
// ---------------------------------------------------------------------------
__global__ __launch_bounds__(256) void state_scan(
    const ushort* __restrict__ fkB, const ushort* __restrict__ VTb,
    ushort* __restrict__ SpreB, float* __restrict__ Kpre) {
    __shared__ __align__(16) ushort fks[64 * 64];   // [l][f]
    __shared__ __align__(16) ushort vts[8 * 64];    // [dloc][l]
    const int h = blockIdx.x, eb = blockIdx.y, t = threadIdx.x;
    const int dr0 = eb * 8;
    const int dloc = t >> 5, f = (t * 2) & 63;
    float run0 = 0.f, run1 = 0.f, rk = 0.f;

    for (int c = 0; c < NCH; ++c) {
        __syncthreads();   // previous chunk's LDS reads done
        {
            const int e = t * 16;
            const size_t fb = ((size_t)h * LQ + c * CT) * FDM;
            *(uint4*)&fks[e]     = *(const uint4*)&fkB[fb + e];
            *(uint4*)&fks[e + 8] = *(const uint4*)&fkB[fb + e + 8];
            if (t < 64) {
                const size_t vb = (((size_t)h * NCH + c) * 64 + dr0) * 64;
                *(uint4*)&vts[t * 8] = *(const uint4*)&VTb[vb + t * 8];
            }
        }
        __syncthreads();

        // exclusive prefix: write BEFORE accumulating this chunk
        const size_t sbase = ((size_t)h * NCH + c) * 4096 + dr0 * 64 + t * 2;
        ushort2 pr = make_ushort2(f2b_raw(run0), f2b_raw(run1));
        *(ushort2*)&SpreB[sbase] = pr;

#pragma unroll 8
        for (int l = 0; l < 64; ++l) {
            const float vt = b2f(vts[dloc * 64 + l]);
            run0 += vt * b2f(fks[l * 64 + f]);
            run1 += vt * b2f(fks[l * 64 + f + 1]);
        }
        if (eb == 0 && t < 64) {
            Kpre[((size_t)h * NCH + c) * FDM + t] = rk;
            float s = 0.f;
#pragma unroll 8
            for (int l = 0; l < 64; ++l) s += b2f(fks[l * 64 + t]);
            rk += s;
        }
    }
}

// ---------------------------------------------------------------------------
// Intra-chunk attention via MFMA.
// ---------------------------------------------------------------------------
__global__ __launch_bounds__(256) void intra2(
    const ushort* __restrict__ fqB, const ushort* __restrict__ fkB,
    const ushort* __restrict__ VTb, const ushort* __restrict__ SpreB,
    const float* __restrict__ Kpre, ushort* __restrict__ Yb) {
    __shared__ __align__(16) ushort fqs[64 * 72];
    __shared__ __align__(16) ushort fks[64 * 72];
    __shared__ __align__(16) ushort VTs[64 * 72];
    __shared__ __align__(16) ushort Sps[64 * 72];
    __shared__ __align__(16) ushort Pms[64 * 72];
    __shared__ float den[64], kpr[64];

    const int c = blockIdx.x, h = blockIdx.y;
    const int t = threadIdx.x, lane = t & 63, wave = t >> 6;
    const int l0 = c * CT;
    const int fr = lane & 15, fo = (lane >> 4) * 8;
    const int g = lane >> 4, cc = lane & 15;

    const size_t qkbase = ((size_t)h * LQ + l0) * FDM;
    const size_t cbase  = ((size_t)h * NCH + c) * 4096;
    for (int it = 0; it < 2; ++it) {
        int e = (it * 256 + t) * 8;
        int row = e >> 6, col = e & 63;
        *(uint4*)&fqs[row * 72 + col] = *(const uint4*)&fqB[qkbase + e];
        *(uint4*)&fks[row * 72 + col] = *(const uint4*)&fkB[qkbase + e];
        *(uint4*)&VTs[row * 72 + col] = *(const uint4*)&VTb[cbase + e];
        *(uint4*)&Sps[row * 72 + col] = *(const uint4*)&SpreB[cbase + e];
    }
    if (t < 64) kpr[t] = Kpre[((size_t)h * NCH + c) * FDM + t];
    __syncthreads();

    // P = fq @ fk^T
    f32x4 accP[4] = {};
#pragma unroll
    for (int kp = 0; kp < 2; ++kp) {
        bf16x8 a = *(const bf16x8*)&fqs[(wave * 16 + fr) * 72 + kp * 32 + fo];
#pragma unroll
        for (int j = 0; j < 4; ++j) {
            bf16x8 b = *(const bf16x8*)&fks[(j * 16 + fr) * 72 + kp * 32 + fo];
            accP[j] = __builtin_amdgcn_mfma_f32_16x16x32_bf16(a, b, accP[j], 0, 0, 0);
        }
    }
#pragma unroll
    for (int j = 0; j < 4; ++j)
#pragma unroll
        for (int r = 0; r < 4; ++r) {
            int l = wave * 16 + g * 4 + r, lp = j * 16 + cc;
            Pms[l * 72 + lp] = (lp <= l) ? f2b_raw(accP[j][r]) : (ushort)0;
        }
    __syncthreads();

    // denominator, 4 threads/row
    {
        const int srow = t >> 2, spart = t & 3;
        float s = 0.f;
#pragma unroll
        for (int i = 0; i < 16; ++i) s += b2f(Pms[srow * 72 + spart * 16 + i]);
#pragma unroll
        for (int i = 0; i < 16; ++i) s += b2f(fqs[srow * 72 + spart * 16 + i]) * kpr[spart * 16 + i];
        s += __shfl_xor(s, 1); s += __shfl_xor(s, 2);
        if (spart == 0) den[srow] = s + EPSV;
    }
    __syncthreads();

    // Y = Pm @ V + fq @ Spre^T
    f32x4 accY[4] = {};
#pragma unroll
    for (int kp = 0; kp < 2; ++kp) {
        bf16x8 a = *(const bf16x8*)&Pms[(wave * 16 + fr) * 72 + kp * 32 + fo];
#pragma unroll
        for (int j = 0; j < 4; ++j) {
            bf16x8 b = *(const bf16x8*)&VTs[(j * 16 + fr) * 72 + kp * 32 + fo];
            accY[j] = __builtin_amdgcn_mfma_f32_16x16x32_bf16(a, b, accY[j], 0, 0, 0);
        }
    }
#pragma unroll
    for (int kp = 0; kp < 2; ++kp) {
        bf16x8 a = *(const bf16x8*)&fqs[(wave * 16 + fr) * 72 + kp * 32 + fo];
#pragma unroll
        for (int j = 0; j < 4; ++j) {
            bf16x8 b = *(const bf16x8*)&Sps[(j * 16 + fr) * 72 + kp * 32 + fo];
            accY[j] = __builtin_amdgcn_mfma_f32_16x16x32_bf16(a, b, accY[j], 0, 0, 0);
        }
    }
#pragma unroll
    for (int r = 0; r < 4; ++r) {
        int l = wave * 16 + g * 4 + r;
        float inv = 1.0f / den[l];
        ushort* yo = Yb + (size_t)(l0 + l) * HID + h * HDM;
#pragma unroll
        for (int j = 0; j < 4; ++j)
            yo[j * 16 + cc] = f2b_raw(accY[j][r] * inv);
    }
}

// ---------------------------------------------------------------------------
extern "C" void kernel_launch(void* const* d_in, const int* in_sizes, int n_in,
                              void* d_out, int out_size, void* d_ws, size_t ws_size,
                              hipStream_t stream) {
    const float* hs  = (const float*)d_in[0];
    const float* Wq  = (const float*)d_in[1];
    const float* Wk  = (const float*)d_in[2];
    const float* Wv  = (const float*)d_in[3];
    const float* Wo  = (const float*)d_in[4];
    const float* Wfq = (const float*)d_in[5];
    const float* Wfk = (const float*)d_in[6];
    float* out = (float*)d_out;

    const size_t SZ = (size_t)LQ * HID;          // 2,097,152
    const size_t WZ = (size_t)HID * HID;         // 4,194,304

    char* w = (char*)d_ws;
    auto aus = [&](size_t n) { ushort* p = (ushort*)w; w += n * sizeof(ushort); return p; };
    auto afl = [&](size_t n) { float*  p = (float*)w;  w += n * sizeof(float);  return p; };

    ushort* hsb   = aus(SZ);
    ushort* wqb   = aus(WZ);
    ushort* wkb   = aus(WZ);
    ushort* wvb   = aus(WZ);
    ushort* wob   = aus(WZ);
    ushort* fqB   = aus(SZ);
    ushort* fkB   = aus(SZ);
    ushort* VTb   = aus(SZ);
    ushort* WfqT  = aus((size_t)NH * 4096);
    ushort* WfkT  = aus((size_t)NH * 4096);
    ushort* SpreB = aus(SZ);
    ushort* Yb    = aus(SZ);
    float*  Kpre  = afl((size_t)NH * NCH * FDM);

    ConvArgs ca;
    ca.src[0] = hs; ca.dst[0] = hsb; ca.n[0] = (int)SZ;
    ca.src[1] = Wq; ca.dst[1] = wqb; ca.n[1] = (int)WZ;
    ca.src[2] = Wk; ca.dst[2] = wkb; ca.n[2] = (int)WZ;
    ca.src[3] = Wv; ca.dst[3] = wvb; ca.n[3] = (int)WZ;
    ca.src[4] = Wo; ca.dst[4] = wob; ca.n[4] = (int)WZ;
    ca.Wfq = Wfq; ca.Wfk = Wfk; ca.WfqT = WfqT; ca.WfkT = WfkT;
    conv_all<<<dim3((unsigned)(WZ / 1024), 7), 256, 0, stream>>>(ca);

    // 128x128 m97-style tiles: grid (16, 8, 3) = 384 blocks
    gemm_qkv_fm<<<dim3(HID / 128, LQ / 128, 3), 256, 0, stream>>>(
        hsb, wqb, wkb, wvb, WfqT, WfkT, fqB, fkB, VTb);

    state_scan<<<dim3(NH, 8), 256, 0, stream>>>(fkB, VTb, SpreB, Kpre);

    intra2<<<dim3(NCH, NH), 256, 0, stream>>>(fqB, fkB, VTb, SpreB, Kpre, Yb);

    gemm_one<<<dim3(HID / 128, LQ / 64), 256, 0, stream>>>(Yb, wob, out);
}

// Round 8
// 224.678 us; speedup vs baseline: 1.1530x; 1.1530x over previous
//
#include <hip/hip_runtime.h>
#include <math.h>

// Problem constants
constexpr int LQ  = 1024;   // sequence length
constexpr int NH  = 32;     // heads
constexpr int HDM = 64;     // head dim
constexpr int FDM = 64;     // feature dim
constexpr int HID = 2048;   // NH*HDM
constexpr int NCH = 16;     // chunks
constexpr int CT  = 64;     // chunk length (NCH*CT == LQ)
#define EPSV 1e-12f

typedef __bf16 bf16x8 __attribute__((ext_vector_type(8)));
typedef float  f32x4  __attribute__((ext_vector_type(4)));

// fp32 -> bf16 raw bits, round-to-nearest-even
__device__ __forceinline__ unsigned short f2b_raw(float x) {
    union { float f; unsigned int u; } v; v.f = x;
    unsigned int r = v.u + 0x7fffu + ((v.u >> 16) & 1u);
    return (unsigned short)(r >> 16);
}
__device__ __forceinline__ float b2f(ushort u) {
    union { unsigned int i; float f; } v; v.i = ((unsigned int)u) << 16; return v.f;
}

// async global->LDS, 16B per lane; lds dst = wave-uniform base + lane*16
#define ASYNC16(ldsp, gp) __builtin_amdgcn_global_load_lds( \
    (const __attribute__((address_space(1))) void*)(gp),    \
    (__attribute__((address_space(3))) void*)(ldsp), 16, 0, 0)

// ---------------------------------------------------------------------------
// Generic bf16 MFMA GEMM core (NT), BK=64, double-buffered, XOR-swizzled LDS.
// NOTE (R7 post-mortem): at M=1024 the 128x128 m97 tile can only fill
// 1.5 blocks/CU and VGPR jumps to 140 -> 8% occupancy, 2x SLOWER. The
// 64x128 dbuf shape (VGPR 68, ~24% occ) is the verified optimum here.
// ---------------------------------------------------------------------------
template <int TM, int TN, bool BF16OUT>
__device__ __forceinline__ void gemm_core(const ushort* __restrict__ A,
                                          const ushort* __restrict__ B,
                                          void* __restrict__ Cv,
                                          int M, int N, int K) {
    constexpr int FI = TM / 32, FJ = TN / 32;
    constexpr int AI = TM / 32, BJ = TN / 32;
    constexpr int ASZ = TM * 64, BSZ = TN * 64;
    __shared__ __align__(16) ushort As[2 * ASZ];
    __shared__ __align__(16) ushort Bs[2 * BSZ];

    const int t = threadIdx.x, wave = t >> 6, lane = t & 63;
    const int wr = (wave >> 1) * (TM / 2), wc = (wave & 1) * (TN / 2);
    const int bm = blockIdx.y * TM, bn = blockIdx.x * TN;

    const int grow = lane >> 3;
    const int gsw  = ((lane & 7) ^ (grow & 7)) << 3;
    const int arow0 = wave * (TM / 4), brow0 = wave * (TN / 4);
    const ushort* gA = A + (size_t)(bm + arow0 + grow) * K + gsw;
    const ushort* gB = B + (size_t)(bn + brow0 + grow) * K + gsw;

    const int fr = lane & 15, q = lane >> 4;

    f32x4 acc[FI][FJ] = {};
    const int NIT = K >> 6;

    {
        ushort* ab = As + arow0 * 64;
        ushort* bb = Bs + brow0 * 64;
#pragma unroll
        for (int i = 0; i < AI; ++i) ASYNC16(ab + i * 512, gA + (size_t)i * 8 * K);
#pragma unroll
        for (int j = 0; j < BJ; ++j) ASYNC16(bb + j * 512, gB + (size_t)j * 8 * K);
    }
    __syncthreads();

    for (int it = 0; it < NIT; ++it) {
        const int p = it & 1;
        if (it + 1 < NIT) {
            const int ko = (it + 1) << 6;
            ushort* ab = As + (p ^ 1) * ASZ + arow0 * 64;
            ushort* bb = Bs + (p ^ 1) * BSZ + brow0 * 64;
#pragma unroll
            for (int i = 0; i < AI; ++i) ASYNC16(ab + i * 512, gA + ko + (size_t)i * 8 * K);
#pragma unroll
            for (int j = 0; j < BJ; ++j) ASYNC16(bb + j * 512, gB + ko + (size_t)j * 8 * K);
        }
        const ushort* ap = As + p * ASZ;
        const ushort* bp = Bs + p * BSZ;
        bf16x8 af[2][FI], bg[2][FJ];
#pragma unroll
        for (int ks = 0; ks < 2; ++ks) {
#pragma unroll
            for (int i = 0; i < FI; ++i) {
                const int row = wr + i * 16 + fr;
                af[ks][i] = *(const bf16x8*)&ap[row * 64 + (((q + ks * 4) ^ (row & 7)) << 3)];
            }
#pragma unroll
            for (int j = 0; j < FJ; ++j) {
                const int row = wc + j * 16 + fr;
                bg[ks][j] = *(const bf16x8*)&bp[row * 64 + (((q + ks * 4) ^ (row & 7)) << 3)];
            }
        }
#pragma unroll
        for (int ks = 0; ks < 2; ++ks)
#pragma unroll
            for (int i = 0; i < FI; ++i)
#pragma unroll
                for (int j = 0; j < FJ; ++j)
                    acc[i][j] = __builtin_amdgcn_mfma_f32_16x16x32_bf16(af[ks][i], bg[ks][j], acc[i][j], 0, 0, 0);
        if (it + 1 < NIT) __syncthreads();
    }

    const int er = q * 4, ec = lane & 15;
#pragma unroll
    for (int i = 0; i < FI; ++i)
#pragma unroll
        for (int j = 0; j < FJ; ++j) {
            const size_t base = (size_t)(bm + wr + i * 16 + er) * N + bn + wc + j * 16 + ec;
            if constexpr (BF16OUT) {
                ushort* C = (ushort*)Cv;
#pragma unroll
                for (int r = 0; r < 4; ++r) C[base + (size_t)r * N] = f2b_raw(acc[i][j][r]);
            } else {
                float* C = (float*)Cv;
#pragma unroll
                for (int r = 0; r < 4; ++r) C[base + (size_t)r * N] = acc[i][j][r];
            }
        }
}

__global__ __launch_bounds__(256) void gemm_one(const ushort* __restrict__ A,
                                                const ushort* __restrict__ B,
                                                float* __restrict__ C) {
    gemm_core<64, 64, false>(A, B, C, LQ, HID, HID);
}

// ---------------------------------------------------------------------------
// Fused QKV projection + feature map (z=0: Q->fqB, z=1: K->fkB) or
// transposed V store (z=2: ->VTb [h][c][d][l]).
// Tile 64(M=one chunk) x 128(N=two heads), BK=64, dbuf, XOR swizzle.
// (R6-verified: 39.8 us, VGPR 68, MfmaUtil 27%.)
// ---------------------------------------------------------------------------
__global__ __launch_bounds__(256) void gemm_qkv_fm(
    const ushort* __restrict__ hsb,
    const ushort* __restrict__ wqb, const ushort* __restrict__ wkb,
    const ushort* __restrict__ wvb,
    const ushort* __restrict__ WfqT, const ushort* __restrict__ WfkT,
    ushort* __restrict__ fqB, ushort* __restrict__ fkB,
    ushort* __restrict__ VTb) {
    constexpr int TM = 64, TN = 128;
    constexpr int ASZ = TM * 64, BSZ = TN * 64;       // 4096 / 8192 ushort
    __shared__ __align__(16) ushort lds[2 * ASZ + 2 * BSZ];   // 24576 ushort = 48 KB
    ushort* As = lds;
    ushort* Bs = lds + 2 * ASZ;

    const int z = blockIdx.z;
    const ushort* Bmat = (z == 0) ? wqb : (z == 1) ? wkb : wvb;

    const int t = threadIdx.x, wave = t >> 6, lane = t & 63;
    const int wr = (wave >> 1) * 32, wc = (wave & 1) * 64;
    const int bx = blockIdx.x, c = blockIdx.y;
    const int bm = c * TM, bn = bx * TN, l0 = c * CT;

    const int grow = lane >> 3;
    const int gsw  = ((lane & 7) ^ (grow & 7)) << 3;
    const int arow0 = wave * 16, brow0 = wave * 32;
    const ushort* gA = hsb  + (size_t)(bm + arow0 + grow) * HID + gsw;
    const ushort* gB = Bmat + (size_t)(bn + brow0 + grow) * HID + gsw;

    const int fr = lane & 15, q = lane >> 4, ec = lane & 15;

    f32x4 acc[2][4] = {};
    const int NIT = HID >> 6;   // 32

    {
        ushort* ab = As + arow0 * 64;
        ushort* bb = Bs + brow0 * 64;
#pragma unroll
        for (int i = 0; i < 2; ++i) ASYNC16(ab + i * 512, gA + (size_t)i * 8 * HID);
#pragma unroll
        for (int j = 0; j < 4; ++j) ASYNC16(bb + j * 512, gB + (size_t)j * 8 * HID);
    }
    __syncthreads();

    for (int it = 0; it < NIT; ++it) {
        const int p = it & 1;
        if (it + 1 < NIT) {
            const int ko = (it + 1) << 6;
            ushort* ab = As + (p ^ 1) * ASZ + arow0 * 64;
            ushort* bb = Bs + (p ^ 1) * BSZ + brow0 * 64;
#pragma unroll
            for (int i = 0; i < 2; ++i) ASYNC16(ab + i * 512, gA + ko + (size_t)i * 8 * HID);
#pragma unroll
            for (int j = 0; j < 4; ++j) ASYNC16(bb + j * 512, gB + ko + (size_t)j * 8 * HID);
        }
        const ushort* ap = As + p * ASZ;
        const ushort* bp = Bs + p * BSZ;
        bf16x8 af[2][2], bg[2][4];
#pragma unroll
        for (int ks = 0; ks < 2; ++ks) {
#pragma unroll
            for (int i = 0; i < 2; ++i) {
                const int row = wr + i * 16 + fr;
                af[ks][i] = *(const bf16x8*)&ap[row * 64 + (((q + ks * 4) ^ (row & 7)) << 3)];
            }
#pragma unroll
            for (int j = 0; j < 4; ++j) {
                const int row = wc + j * 16 + fr;
                bg[ks][j] = *(const bf16x8*)&bp[row * 64 + (((q + ks * 4) ^ (row & 7)) << 3)];
            }
        }
#pragma unroll
        for (int ks = 0; ks < 2; ++ks)
#pragma unroll
            for (int i = 0; i < 2; ++i)
#pragma unroll
                for (int j = 0; j < 4; ++j)
                    acc[i][j] = __builtin_amdgcn_mfma_f32_16x16x32_bf16(af[ks][i], bg[ks][j], acc[i][j], 0, 0, 0);
        if (it + 1 < NIT) __syncthreads();
    }

    if (z == 2) {
        // transposed V store: r is contiguous in l -> ushort4
#pragma unroll
        for (int i = 0; i < 2; ++i)
#pragma unroll
            for (int j = 0; j < 4; ++j) {
                const int col = wc + j * 16 + ec;        // 0..127
                const int hh = col >> 6, d = col & 63;
                const int lb = wr + i * 16 + q * 4;
                const size_t base = (((size_t)(2 * bx + hh) * NCH + c) * 64 + d) * 64 + lb;
                ushort4 o = make_ushort4(f2b_raw(acc[i][j][0]), f2b_raw(acc[i][j][1]),
                                         f2b_raw(acc[i][j][2]), f2b_raw(acc[i][j][3]));
                *(ushort4*)&VTb[base] = o;
            }
        return;
    }

    // ---- fused feature map ----
    __syncthreads();                       // all LDS reads of K-loop done
    ushort* Qt  = lds;                     // [64][136] bf16 projection tile
    ushort* Wfs = lds + 8704;              // [2][64][72] WfT for heads 2bx,2bx+1
#pragma unroll
    for (int i = 0; i < 2; ++i)
#pragma unroll
        for (int j = 0; j < 4; ++j)
#pragma unroll
            for (int r = 0; r < 4; ++r)
                Qt[(wr + i * 16 + q * 4 + r) * 136 + wc + j * 16 + ec] = f2b_raw(acc[i][j][r]);
    {
        const ushort* WT = ((z == 0) ? WfqT : WfkT) + (size_t)(2 * bx) * 4096;
#pragma unroll
        for (int it = 0; it < 4; ++it) {
            const int e = it * 2048 + t * 8;
            const int hh = e >> 12, f = (e >> 6) & 63, dc = e & 63;
            uint4 wv4 = *(const uint4*)&WT[e];
            *(uint4*)&Wfs[hh * 4608 + f * 72 + dc] = wv4;
        }
    }
    __syncthreads();

    // Z = Qhead @ WfT^T  : wave -> head (wave&1), rows (wave>>1)*32..+32
    const int hh = wave & 1, R0 = (wave >> 1) * 32;
    f32x4 z2[2][4] = {};
#pragma unroll
    for (int ks = 0; ks < 2; ++ks) {
        bf16x8 a[2];
#pragma unroll
        for (int i = 0; i < 2; ++i)
            a[i] = *(const bf16x8*)&Qt[(R0 + i * 16 + fr) * 136 + hh * 64 + ks * 32 + q * 8];
#pragma unroll
        for (int j = 0; j < 4; ++j) {
            bf16x8 b = *(const bf16x8*)&Wfs[hh * 4608 + (j * 16 + fr) * 72 + ks * 32 + q * 8];
#pragma unroll
            for (int i = 0; i < 2; ++i)
                z2[i][j] = __builtin_amdgcn_mfma_f32_16x16x32_bf16(a[i], b, z2[i][j], 0, 0, 0);
        }
    }

    // softmax over f per row, entirely in registers (16-lane quad groups)
    ushort* outp = (z == 0) ? fqB : fkB;
    const int hgl = 2 * bx + hh;
#pragma unroll
    for (int i = 0; i < 2; ++i)
#pragma unroll
        for (int r = 0; r < 4; ++r) {
            float m = z2[i][0][r];
#pragma unroll
            for (int j = 1; j < 4; ++j) m = fmaxf(m, z2[i][j][r]);
            m = fmaxf(m, __shfl_xor(m, 1)); m = fmaxf(m, __shfl_xor(m, 2));
            m = fmaxf(m, __shfl_xor(m, 4)); m = fmaxf(m, __shfl_xor(m, 8));
            float e4[4], s = 0.f;
#pragma unroll
            for (int j = 0; j < 4; ++j) { e4[j] = __expf(z2[i][j][r] - m); s += e4[j]; }
            s += __shfl_xor(s, 1); s += __shfl_xor(s, 2);
            s += __shfl_xor(s, 4); s += __shfl_xor(s, 8);
            const float inv = 1.0f / s;
            const int l = R0 + i * 16 + q * 4 + r;
            ushort* op = outp + ((size_t)hgl * LQ + l0 + l) * FDM;
#pragma unroll
            for (int j = 0; j < 4; ++j) op[j * 16 + ec] = f2b_raw(e4[j] * inv);
        }
}

// ---------------------------------------------------------------------------
// Convert: y=0..4 fp32->bf16 tensors; y=5,6 Wf transpose (h = blockIdx.x < 32)
// ---------------------------------------------------------------------------
struct ConvArgs {
    const float* src[5]; ushort* dst[5]; int n[5];
    const float* Wfq; const float* Wfk; ushort* WfqT; ushort* WfkT;
};
__global__ __launch_bounds__(256) void conv_all(ConvArgs p) {
    const int y = blockIdx.y, t = threadIdx.x;
    if (y < 5) {
        const int i = (blockIdx.x * 256 + t) * 4;
        if (i >= p.n[y]) return;
        float4 v = *(const float4*)&p.src[y][i];
        ushort4 o = make_ushort4(f2b_raw(v.x), f2b_raw(v.y), f2b_raw(v.z), f2b_raw(v.w));
        *(ushort4*)&p.dst[y][i] = o;
        return;
    }
    if (blockIdx.x >= NH) return;
    const int h = blockIdx.x;
    const float* src = ((y == 6) ? p.Wfk : p.Wfq) + (size_t)h * 4096;  // [d][f]
    ushort* dst = ((y == 6) ? p.WfkT : p.WfqT) + (size_t)h * 4096;     // [f][d]
    __shared__ float tile[64][65];
    for (int it = 0; it < 16; ++it) {
        int e = it * 256 + t; int d = e >> 6, f = e & 63;
        tile[d][f] = src[e];
    }
    __syncthreads();
    for (int it = 0; it < 16; ++it) {
        int e = it * 256 + t; int f = e >> 6, d = e & 63;
        dst[e] = f2b_raw(tile[d][f]);
    }
}

// ---------------------------------------------------------------------------
// Fused chunk-state + exclusive prefix scan. grid (NH, 8), block 256.
// ---------------------------------------------------------------------------
__global__ __launch_bounds__(256) void state_scan(
    const ushort* __restrict__ fkB, const ushort* __restrict__ VTb,
    ushort* __restrict__ SpreB, float* __restrict__ Kpre) {
    __shared__ __align__(16) ushort fks[64 * 64];   // [l][f]
    __shared__ __align__(16) ushort vts[8 * 64];    // [dloc][l]
    const int h = blockIdx.x, eb = blockIdx.y, t = threadIdx.x;
    const int dr0 = eb * 8;
    const int dloc = t >> 5, f = (t * 2) & 63;
    float run0 = 0.f, run1 = 0.f, rk = 0.f;

    for (int c = 0; c < NCH; ++c) {
        __syncthreads();   // previous chunk's LDS reads done
        {
            const int e = t * 16;
            const size_t fb = ((size_t)h * LQ + c * CT) * FDM;
            *(uint4*)&fks[e]     = *(const uint4*)&fkB[fb + e];
            *(uint4*)&fks[e + 8] = *(const uint4*)&fkB[fb + e + 8];
            if (t < 64) {
                const size_t vb = (((size_t)h * NCH + c) * 64 + dr0) * 64;
                *(uint4*)&vts[t * 8] = *(const uint4*)&VTb[vb + t * 8];
            }
        }
        __syncthreads();

        // exclusive prefix: write BEFORE accumulating this chunk
        const size_t sbase = ((size_t)h * NCH + c) * 4096 + dr0 * 64 + t * 2;
        ushort2 pr = make_ushort2(f2b_raw(run0), f2b_raw(run1));
        *(ushort2*)&SpreB[sbase] = pr;

#pragma unroll 8
        for (int l = 0; l < 64; ++l) {
            const float vt = b2f(vts[dloc * 64 + l]);
            run0 += vt * b2f(fks[l * 64 + f]);
            run1 += vt * b2f(fks[l * 64 + f + 1]);
        }
        if (eb == 0 && t < 64) {
            Kpre[((size_t)h * NCH + c) * FDM + t] = rk;
            float s = 0.f;
#pragma unroll 8
            for (int l = 0; l < 64; ++l) s += b2f(fks[l * 64 + t]);
            rk += s;
        }
    }
}

// ---------------------------------------------------------------------------
// Intra-chunk attention via MFMA.
// ---------------------------------------------------------------------------
__global__ __launch_bounds__(256) void intra2(
    const ushort* __restrict__ fqB, const ushort* __restrict__ fkB,
    const ushort* __restrict__ VTb, const ushort* __restrict__ SpreB,
    const float* __restrict__ Kpre, ushort* __restrict__ Yb) {
    __shared__ __align__(16) ushort fqs[64 * 72];
    __shared__ __align__(16) ushort fks[64 * 72];
    __shared__ __align__(16) ushort VTs[64 * 72];
    __shared__ __align__(16) ushort Sps[64 * 72];
    __shared__ __align__(16) ushort Pms[64 * 72];
    __shared__ float den[64], kpr[64];

    const int c = blockIdx.x, h = blockIdx.y;
    const int t = threadIdx.x, lane = t & 63, wave = t >> 6;
    const int l0 = c * CT;
    const int fr = lane & 15, fo = (lane >> 4) * 8;
    const int g = lane >> 4, cc = lane & 15;

    const size_t qkbase = ((size_t)h * LQ + l0) * FDM;
    const size_t cbase  = ((size_t)h * NCH + c) * 4096;
    for (int it = 0; it < 2; ++it) {
        int e = (it * 256 + t) * 8;
        int row = e >> 6, col = e & 63;
        *(uint4*)&fqs[row * 72 + col] = *(const uint4*)&fqB[qkbase + e];
        *(uint4*)&fks[row * 72 + col] = *(const uint4*)&fkB[qkbase + e];
        *(uint4*)&VTs[row * 72 + col] = *(const uint4*)&VTb[cbase + e];
        *(uint4*)&Sps[row * 72 + col] = *(const uint4*)&SpreB[cbase + e];
    }
    if (t < 64) kpr[t] = Kpre[((size_t)h * NCH + c) * FDM + t];
    __syncthreads();

    // P = fq @ fk^T
    f32x4 accP[4] = {};
#pragma unroll
    for (int kp = 0; kp < 2; ++kp) {
        bf16x8 a = *(const bf16x8*)&fqs[(wave * 16 + fr) * 72 + kp * 32 + fo];
#pragma unroll
        for (int j = 0; j < 4; ++j) {
            bf16x8 b = *(const bf16x8*)&fks[(j * 16 + fr) * 72 + kp * 32 + fo];
            accP[j] = __builtin_amdgcn_mfma_f32_16x16x32_bf16(a, b, accP[j], 0, 0, 0);
        }
    }
#pragma unroll
    for (int j = 0; j < 4; ++j)
#pragma unroll
        for (int r = 0; r < 4; ++r) {
            int l = wave * 16 + g * 4 + r, lp = j * 16 + cc;
            Pms[l * 72 + lp] = (lp <= l) ? f2b_raw(accP[j][r]) : (ushort)0;
        }
    __syncthreads();

    // denominator, 4 threads/row
    {
        const int srow = t >> 2, spart = t & 3;
        float s = 0.f;
#pragma unroll
        for (int i = 0; i < 16; ++i) s += b2f(Pms[srow * 72 + spart * 16 + i]);
#pragma unroll
        for (int i = 0; i < 16; ++i) s += b2f(fqs[srow * 72 + spart * 16 + i]) * kpr[spart * 16 + i];
        s += __shfl_xor(s, 1); s += __shfl_xor(s, 2);
        if (spart == 0) den[srow] = s + EPSV;
    }
    __syncthreads();

    // Y = Pm @ V + fq @ Spre^T
    f32x4 accY[4] = {};
#pragma unroll
    for (int kp = 0; kp < 2; ++kp) {
        bf16x8 a = *(const bf16x8*)&Pms[(wave * 16 + fr) * 72 + kp * 32 + fo];
#pragma unroll
        for (int j = 0; j < 4; ++j) {
            bf16x8 b = *(const bf16x8*)&VTs[(j * 16 + fr) * 72 + kp * 32 + fo];
            accY[j] = __builtin_amdgcn_mfma_f32_16x16x32_bf16(a, b, accY[j], 0, 0, 0);
        }
    }
#pragma unroll
    for (int kp = 0; kp < 2; ++kp) {
        bf16x8 a = *(const bf16x8*)&fqs[(wave * 16 + fr) * 72 + kp * 32 + fo];
#pragma unroll
        for (int j = 0; j < 4; ++j) {
            bf16x8 b = *(const bf16x8*)&Sps[(j * 16 + fr) * 72 + kp * 32 + fo];
            accY[j] = __builtin_amdgcn_mfma_f32_16x16x32_bf16(a, b, accY[j], 0, 0, 0);
        }
    }
#pragma unroll
    for (int r = 0; r < 4; ++r) {
        int l = wave * 16 + g * 4 + r;
        float inv = 1.0f / den[l];
        ushort* yo = Yb + (size_t)(l0 + l) * HID + h * HDM;
#pragma unroll
        for (int j = 0; j < 4; ++j)
            yo[j * 16 + cc] = f2b_raw(accY[j][r] * inv);
    }
}

// ---------------------------------------------------------------------------
extern "C" void kernel_launch(void* const* d_in, const int* in_sizes, int n_in,
                              void* d_out, int out_size, void* d_ws, size_t ws_size,
                              hipStream_t stream) {
    const float* hs  = (const float*)d_in[0];
    const float* Wq  = (const float*)d_in[1];
    const float* Wk  = (const float*)d_in[2];
    const float* Wv  = (const float*)d_in[3];
    const float* Wo  = (const float*)d_in[4];
    const float* Wfq = (const float*)d_in[5];
    const float* Wfk = (const float*)d_in[6];
    float* out = (float*)d_out;

    const size_t SZ = (size_t)LQ * HID;          // 2,097,152
    const size_t WZ = (size_t)HID * HID;         // 4,194,304

    char* w = (char*)d_ws;
    auto aus = [&](size_t n) { ushort* p = (ushort*)w; w += n * sizeof(ushort); return p; };
    auto afl = [&](size_t n) { float*  p = (float*)w;  w += n * sizeof(float);  return p; };

    ushort* hsb   = aus(SZ);
    ushort* wqb   = aus(WZ);
    ushort* wkb   = aus(WZ);
    ushort* wvb   = aus(WZ);
    ushort* wob   = aus(WZ);
    ushort* fqB   = aus(SZ);
    ushort* fkB   = aus(SZ);
    ushort* VTb   = aus(SZ);
    ushort* WfqT  = aus((size_t)NH * 4096);
    ushort* WfkT  = aus((size_t)NH * 4096);
    ushort* SpreB = aus(SZ);
    ushort* Yb    = aus(SZ);
    float*  Kpre  = afl((size_t)NH * NCH * FDM);

    ConvArgs ca;
    ca.src[0] = hs; ca.dst[0] = hsb; ca.n[0] = (int)SZ;
    ca.src[1] = Wq; ca.dst[1] = wqb; ca.n[1] = (int)WZ;
    ca.src[2] = Wk; ca.dst[2] = wkb; ca.n[2] = (int)WZ;
    ca.src[3] = Wv; ca.dst[3] = wvb; ca.n[3] = (int)WZ;
    ca.src[4] = Wo; ca.dst[4] = wob; ca.n[4] = (int)WZ;
    ca.Wfq = Wfq; ca.Wfk = Wfk; ca.WfqT = WfqT; ca.WfkT = WfkT;
    conv_all<<<dim3((unsigned)(WZ / 1024), 7), 256, 0, stream>>>(ca);

    // 64x128 tiles: grid (16, 16, 3) = 768 blocks = 3 blocks/CU
    gemm_qkv_fm<<<dim3(HID / 128, LQ / 64, 3), 256, 0, stream>>>(
        hsb, wqb, wkb, wvb, WfqT, WfkT, fqB, fkB, VTb);

    state_scan<<<dim3(NH, 8), 256, 0, stream>>>(fkB, VTb, SpreB, Kpre);

    intra2<<<dim3(NCH, NH), 256, 0, stream>>>(fqB, fkB, VTb, SpreB, Kpre, Yb);

    // 64x64 tile: grid 32 x 16 = 512 blocks = 2 blocks/CU
    gemm_one<<<dim3(HID / 64, LQ / 64), 256, 0, stream>>>(Yb, wob, out);
}

// Round 9
// 195.237 us; speedup vs baseline: 1.3268x; 1.1508x over previous
//
#include <hip/hip_runtime.h>
#include <math.h>

// Problem constants
constexpr int LQ  = 1024;   // sequence length
constexpr int NH  = 32;     // heads
constexpr int HDM = 64;     // head dim
constexpr int FDM = 64;     // feature dim
constexpr int HID = 2048;   // NH*HDM
constexpr int NCH = 16;     // chunks
constexpr int CT  = 64;     // chunk length (NCH*CT == LQ)
#define EPSV 1e-12f

typedef __bf16 bf16x8 __attribute__((ext_vector_type(8)));
typedef float  f32x4  __attribute__((ext_vector_type(4)));

// fp32 -> bf16 raw bits, round-to-nearest-even
__device__ __forceinline__ unsigned short f2b_raw(float x) {
    union { float f; unsigned int u; } v; v.f = x;
    unsigned int r = v.u + 0x7fffu + ((v.u >> 16) & 1u);
    return (unsigned short)(r >> 16);
}
__device__ __forceinline__ float b2f(ushort u) {
    union { unsigned int i; float f; } v; v.i = ((unsigned int)u) << 16; return v.f;
}

// async global->LDS, 16B per lane; lds dst = wave-uniform base + lane*16
#define ASYNC16(ldsp, gp) __builtin_amdgcn_global_load_lds( \
    (const __attribute__((address_space(1))) void*)(gp),    \
    (__attribute__((address_space(3))) void*)(ldsp), 16, 0, 0)

// ---------------------------------------------------------------------------
// Generic bf16 MFMA GEMM core (NT), BK=64, double-buffered, XOR-swizzled LDS.
// NOTE (R7): 128x128 tile at M=1024 -> 1.5 blk/CU, VGPR 140 -> 2x slower.
// NOTE (R8): replacing chunk_state+prefix2 with a scalar register scan cost
// +30 us (serial LDS-latency chain). Keep MFMA for anything matmul-shaped.
// ---------------------------------------------------------------------------
template <int TM, int TN, bool BF16OUT>
__device__ __forceinline__ void gemm_core(const ushort* __restrict__ A,
                                          const ushort* __restrict__ B,
                                          void* __restrict__ Cv,
                                          int M, int N, int K) {
    constexpr int FI = TM / 32, FJ = TN / 32;
    constexpr int AI = TM / 32, BJ = TN / 32;
    constexpr int ASZ = TM * 64, BSZ = TN * 64;
    __shared__ __align__(16) ushort As[2 * ASZ];
    __shared__ __align__(16) ushort Bs[2 * BSZ];

    const int t = threadIdx.x, wave = t >> 6, lane = t & 63;
    const int wr = (wave >> 1) * (TM / 2), wc = (wave & 1) * (TN / 2);
    const int bm = blockIdx.y * TM, bn = blockIdx.x * TN;

    const int grow = lane >> 3;
    const int gsw  = ((lane & 7) ^ (grow & 7)) << 3;
    const int arow0 = wave * (TM / 4), brow0 = wave * (TN / 4);
    const ushort* gA = A + (size_t)(bm + arow0 + grow) * K + gsw;
    const ushort* gB = B + (size_t)(bn + brow0 + grow) * K + gsw;

    const int fr = lane & 15, q = lane >> 4;

    f32x4 acc[FI][FJ] = {};
    const int NIT = K >> 6;

    {
        ushort* ab = As + arow0 * 64;
        ushort* bb = Bs + brow0 * 64;
#pragma unroll
        for (int i = 0; i < AI; ++i) ASYNC16(ab + i * 512, gA + (size_t)i * 8 * K);
#pragma unroll
        for (int j = 0; j < BJ; ++j) ASYNC16(bb + j * 512, gB + (size_t)j * 8 * K);
    }
    __syncthreads();

    for (int it = 0; it < NIT; ++it) {
        const int p = it & 1;
        if (it + 1 < NIT) {
            const int ko = (it + 1) << 6;
            ushort* ab = As + (p ^ 1) * ASZ + arow0 * 64;
            ushort* bb = Bs + (p ^ 1) * BSZ + brow0 * 64;
#pragma unroll
            for (int i = 0; i < AI; ++i) ASYNC16(ab + i * 512, gA + ko + (size_t)i * 8 * K);
#pragma unroll
            for (int j = 0; j < BJ; ++j) ASYNC16(bb + j * 512, gB + ko + (size_t)j * 8 * K);
        }
        const ushort* ap = As + p * ASZ;
        const ushort* bp = Bs + p * BSZ;
        bf16x8 af[2][FI], bg[2][FJ];
#pragma unroll
        for (int ks = 0; ks < 2; ++ks) {
#pragma unroll
            for (int i = 0; i < FI; ++i) {
                const int row = wr + i * 16 + fr;
                af[ks][i] = *(const bf16x8*)&ap[row * 64 + (((q + ks * 4) ^ (row & 7)) << 3)];
            }
#pragma unroll
            for (int j = 0; j < FJ; ++j) {
                const int row = wc + j * 16 + fr;
                bg[ks][j] = *(const bf16x8*)&bp[row * 64 + (((q + ks * 4) ^ (row & 7)) << 3)];
            }
        }
#pragma unroll
        for (int ks = 0; ks < 2; ++ks)
#pragma unroll
            for (int i = 0; i < FI; ++i)
#pragma unroll
                for (int j = 0; j < FJ; ++j)
                    acc[i][j] = __builtin_amdgcn_mfma_f32_16x16x32_bf16(af[ks][i], bg[ks][j], acc[i][j], 0, 0, 0);
        if (it + 1 < NIT) __syncthreads();
    }

    const int er = q * 4, ec = lane & 15;
#pragma unroll
    for (int i = 0; i < FI; ++i)
#pragma unroll
        for (int j = 0; j < FJ; ++j) {
            const size_t base = (size_t)(bm + wr + i * 16 + er) * N + bn + wc + j * 16 + ec;
            if constexpr (BF16OUT) {
                ushort* C = (ushort*)Cv;
#pragma unroll
                for (int r = 0; r < 4; ++r) C[base + (size_t)r * N] = f2b_raw(acc[i][j][r]);
            } else {
                float* C = (float*)Cv;
#pragma unroll
                for (int r = 0; r < 4; ++r) C[base + (size_t)r * N] = acc[i][j][r];
            }
        }
}

__global__ __launch_bounds__(256) void gemm_one(const ushort* __restrict__ A,
                                                const ushort* __restrict__ B,
                                                float* __restrict__ C) {
    gemm_core<64, 64, false>(A, B, C, LQ, HID, HID);
}

// ---------------------------------------------------------------------------
// Fused QKV projection + feature map (z=0: Q->fqB, z=1: K->fkB) or
// transposed V store (z=2: ->VTb [h][c][d][l]).
// Tile 64(M=one chunk) x 128(N=two heads), BK=64, dbuf, XOR swizzle.
// (R6-verified: 39.8 us, VGPR 68, MfmaUtil 27%.)
// ---------------------------------------------------------------------------
__global__ __launch_bounds__(256) void gemm_qkv_fm(
    const ushort* __restrict__ hsb,
    const ushort* __restrict__ wqb, const ushort* __restrict__ wkb,
    const ushort* __restrict__ wvb,
    const ushort* __restrict__ WfqT, const ushort* __restrict__ WfkT,
    ushort* __restrict__ fqB, ushort* __restrict__ fkB,
    ushort* __restrict__ VTb) {
    constexpr int TM = 64, TN = 128;
    constexpr int ASZ = TM * 64, BSZ = TN * 64;       // 4096 / 8192 ushort
    __shared__ __align__(16) ushort lds[2 * ASZ + 2 * BSZ];   // 24576 ushort = 48 KB
    ushort* As = lds;
    ushort* Bs = lds + 2 * ASZ;

    const int z = blockIdx.z;
    const ushort* Bmat = (z == 0) ? wqb : (z == 1) ? wkb : wvb;

    const int t = threadIdx.x, wave = t >> 6, lane = t & 63;
    const int wr = (wave >> 1) * 32, wc = (wave & 1) * 64;
    const int bx = blockIdx.x, c = blockIdx.y;
    const int bm = c * TM, bn = bx * TN, l0 = c * CT;

    const int grow = lane >> 3;
    const int gsw  = ((lane & 7) ^ (grow & 7)) << 3;
    const int arow0 = wave * 16, brow0 = wave * 32;
    const ushort* gA = hsb  + (size_t)(bm + arow0 + grow) * HID + gsw;
    const ushort* gB = Bmat + (size_t)(bn + brow0 + grow) * HID + gsw;

    const int fr = lane & 15, q = lane >> 4, ec = lane & 15;

    f32x4 acc[2][4] = {};
    const int NIT = HID >> 6;   // 32

    {
        ushort* ab = As + arow0 * 64;
        ushort* bb = Bs + brow0 * 64;
#pragma unroll
        for (int i = 0; i < 2; ++i) ASYNC16(ab + i * 512, gA + (size_t)i * 8 * HID);
#pragma unroll
        for (int j = 0; j < 4; ++j) ASYNC16(bb + j * 512, gB + (size_t)j * 8 * HID);
    }
    __syncthreads();

    for (int it = 0; it < NIT; ++it) {
        const int p = it & 1;
        if (it + 1 < NIT) {
            const int ko = (it + 1) << 6;
            ushort* ab = As + (p ^ 1) * ASZ + arow0 * 64;
            ushort* bb = Bs + (p ^ 1) * BSZ + brow0 * 64;
#pragma unroll
            for (int i = 0; i < 2; ++i) ASYNC16(ab + i * 512, gA + ko + (size_t)i * 8 * HID);
#pragma unroll
            for (int j = 0; j < 4; ++j) ASYNC16(bb + j * 512, gB + ko + (size_t)j * 8 * HID);
        }
        const ushort* ap = As + p * ASZ;
        const ushort* bp = Bs + p * BSZ;
        bf16x8 af[2][2], bg[2][4];
#pragma unroll
        for (int ks = 0; ks < 2; ++ks) {
#pragma unroll
            for (int i = 0; i < 2; ++i) {
                const int row = wr + i * 16 + fr;
                af[ks][i] = *(const bf16x8*)&ap[row * 64 + (((q + ks * 4) ^ (row & 7)) << 3)];
            }
#pragma unroll
            for (int j = 0; j < 4; ++j) {
                const int row = wc + j * 16 + fr;
                bg[ks][j] = *(const bf16x8*)&bp[row * 64 + (((q + ks * 4) ^ (row & 7)) << 3)];
            }
        }
#pragma unroll
        for (int ks = 0; ks < 2; ++ks)
#pragma unroll
            for (int i = 0; i < 2; ++i)
#pragma unroll
                for (int j = 0; j < 4; ++j)
                    acc[i][j] = __builtin_amdgcn_mfma_f32_16x16x32_bf16(af[ks][i], bg[ks][j], acc[i][j], 0, 0, 0);
        if (it + 1 < NIT) __syncthreads();
    }

    if (z == 2) {
        // transposed V store: r is contiguous in l -> ushort4
#pragma unroll
        for (int i = 0; i < 2; ++i)
#pragma unroll
            for (int j = 0; j < 4; ++j) {
                const int col = wc + j * 16 + ec;        // 0..127
                const int hh = col >> 6, d = col & 63;
                const int lb = wr + i * 16 + q * 4;
                const size_t base = (((size_t)(2 * bx + hh) * NCH + c) * 64 + d) * 64 + lb;
                ushort4 o = make_ushort4(f2b_raw(acc[i][j][0]), f2b_raw(acc[i][j][1]),
                                         f2b_raw(acc[i][j][2]), f2b_raw(acc[i][j][3]));
                *(ushort4*)&VTb[base] = o;
            }
        return;
    }

    // ---- fused feature map ----
    __syncthreads();                       // all LDS reads of K-loop done
    ushort* Qt  = lds;                     // [64][136] bf16 projection tile
    ushort* Wfs = lds + 8704;              // [2][64][72] WfT for heads 2bx,2bx+1
#pragma unroll
    for (int i = 0; i < 2; ++i)
#pragma unroll
        for (int j = 0; j < 4; ++j)
#pragma unroll
            for (int r = 0; r < 4; ++r)
                Qt[(wr + i * 16 + q * 4 + r) * 136 + wc + j * 16 + ec] = f2b_raw(acc[i][j][r]);
    {
        const ushort* WT = ((z == 0) ? WfqT : WfkT) + (size_t)(2 * bx) * 4096;
#pragma unroll
        for (int it = 0; it < 4; ++it) {
            const int e = it * 2048 + t * 8;
            const int hh = e >> 12, f = (e >> 6) & 63, dc = e & 63;
            uint4 wv4 = *(const uint4*)&WT[e];
            *(uint4*)&Wfs[hh * 4608 + f * 72 + dc] = wv4;
        }
    }
    __syncthreads();

    // Z = Qhead @ WfT^T  : wave -> head (wave&1), rows (wave>>1)*32..+32
    const int hh = wave & 1, R0 = (wave >> 1) * 32;
    f32x4 z2[2][4] = {};
#pragma unroll
    for (int ks = 0; ks < 2; ++ks) {
        bf16x8 a[2];
#pragma unroll
        for (int i = 0; i < 2; ++i)
            a[i] = *(const bf16x8*)&Qt[(R0 + i * 16 + fr) * 136 + hh * 64 + ks * 32 + q * 8];
#pragma unroll
        for (int j = 0; j < 4; ++j) {
            bf16x8 b = *(const bf16x8*)&Wfs[hh * 4608 + (j * 16 + fr) * 72 + ks * 32 + q * 8];
#pragma unroll
            for (int i = 0; i < 2; ++i)
                z2[i][j] = __builtin_amdgcn_mfma_f32_16x16x32_bf16(a[i], b, z2[i][j], 0, 0, 0);
        }
    }

    // softmax over f per row, entirely in registers (16-lane quad groups)
    ushort* outp = (z == 0) ? fqB : fkB;
    const int hgl = 2 * bx + hh;
#pragma unroll
    for (int i = 0; i < 2; ++i)
#pragma unroll
        for (int r = 0; r < 4; ++r) {
            float m = z2[i][0][r];
#pragma unroll
            for (int j = 1; j < 4; ++j) m = fmaxf(m, z2[i][j][r]);
            m = fmaxf(m, __shfl_xor(m, 1)); m = fmaxf(m, __shfl_xor(m, 2));
            m = fmaxf(m, __shfl_xor(m, 4)); m = fmaxf(m, __shfl_xor(m, 8));
            float e4[4], s = 0.f;
#pragma unroll
            for (int j = 0; j < 4; ++j) { e4[j] = __expf(z2[i][j][r] - m); s += e4[j]; }
            s += __shfl_xor(s, 1); s += __shfl_xor(s, 2);
            s += __shfl_xor(s, 4); s += __shfl_xor(s, 8);
            const float inv = 1.0f / s;
            const int l = R0 + i * 16 + q * 4 + r;
            ushort* op = outp + ((size_t)hgl * LQ + l0 + l) * FDM;
#pragma unroll
            for (int j = 0; j < 4; ++j) op[j * 16 + ec] = f2b_raw(e4[j] * inv);
        }
}

// ---------------------------------------------------------------------------
// Convert: y=0..4 fp32->bf16 tensors; y=5,6 Wf transpose (h = blockIdx.x < 32)
// ---------------------------------------------------------------------------
struct ConvArgs {
    const float* src[5]; ushort* dst[5]; int n[5];
    const float* Wfq; const float* Wfk; ushort* WfqT; ushort* WfkT;
};
__global__ __launch_bounds__(256) void conv_all(ConvArgs p) {
    const int y = blockIdx.y, t = threadIdx.x;
    if (y < 5) {
        const int i = (blockIdx.x * 256 + t) * 4;
        if (i >= p.n[y]) return;
        float4 v = *(const float4*)&p.src[y][i];
        ushort4 o = make_ushort4(f2b_raw(v.x), f2b_raw(v.y), f2b_raw(v.z), f2b_raw(v.w));
        *(ushort4*)&p.dst[y][i] = o;
        return;
    }
    if (blockIdx.x >= NH) return;
    const int h = blockIdx.x;
    const float* src = ((y == 6) ? p.Wfk : p.Wfq) + (size_t)h * 4096;  // [d][f]
    ushort* dst = ((y == 6) ? p.WfkT : p.WfqT) + (size_t)h * 4096;     // [f][d]
    __shared__ float tile[64][65];
    for (int it = 0; it < 16; ++it) {
        int e = it * 256 + t; int d = e >> 6, f = e & 63;
        tile[d][f] = src[e];
    }
    __syncthreads();
    for (int it = 0; it < 16; ++it) {
        int e = it * 256 + t; int f = e >> 6, d = e & 63;
        dst[e] = f2b_raw(tile[d][f]);
    }
}

// ---------------------------------------------------------------------------
// Per-chunk KV state via MFMA: St[d][f] = sum_l VT[d][l]*fk[l][f]; Ks[f].
// grid (NCH, NH), block 256.  (R6-verified path.)
// ---------------------------------------------------------------------------
__global__ __launch_bounds__(256) void chunk_state(
    const ushort* __restrict__ fkB, const ushort* __restrict__ VTb,
    float* __restrict__ Sraw, float* __restrict__ Ks) {
    __shared__ __align__(16) ushort Vs[64 * 72];   // [d][l]
    __shared__ __align__(16) ushort Fs[64 * 72];   // [f][l]
    const int c = blockIdx.x, h = blockIdx.y;
    const int t = threadIdx.x, lane = t & 63, w = t >> 6;
    const int l0 = c * CT;
    const int fr = lane & 15, q = lane >> 4, ec = lane & 15;
    const size_t cb = ((size_t)h * NCH + c) * 4096;

    for (int it = 0; it < 2; ++it) {
        const int e = (it * 256 + t) * 8;
        const int row = e >> 6, col = e & 63;
        *(uint4*)&Vs[row * 72 + col] = *(const uint4*)&VTb[cb + e];
        uint4 fv = *(const uint4*)&fkB[((size_t)h * LQ + l0) * FDM + e];
        const ushort* pf = (const ushort*)&fv;
#pragma unroll
        for (int i2 = 0; i2 < 8; ++i2) Fs[(col + i2) * 72 + row] = pf[i2];
    }
    __syncthreads();

    f32x4 acc[4] = {};
#pragma unroll
    for (int ks = 0; ks < 2; ++ks) {
        bf16x8 a = *(const bf16x8*)&Vs[(w * 16 + fr) * 72 + ks * 32 + q * 8];
#pragma unroll
        for (int j = 0; j < 4; ++j) {
            bf16x8 b = *(const bf16x8*)&Fs[(j * 16 + fr) * 72 + ks * 32 + q * 8];
            acc[j] = __builtin_amdgcn_mfma_f32_16x16x32_bf16(a, b, acc[j], 0, 0, 0);
        }
    }
    float* sp = Sraw + cb;
#pragma unroll
    for (int j = 0; j < 4; ++j)
#pragma unroll
        for (int r = 0; r < 4; ++r)
            sp[(w * 16 + q * 4 + r) * 64 + j * 16 + ec] = acc[j][r];
    if (t < 64) {
        float s = 0.f;
#pragma unroll 8
        for (int l = 0; l < 64; ++l) s += b2f(Fs[t * 72 + l]);
        Ks[((size_t)h * NCH + c) * FDM + t] = s;
    }
}

// ---------------------------------------------------------------------------
// Exclusive prefix over chunks; grid (NH, 8), block 256.  (R6-verified path.)
// ---------------------------------------------------------------------------
__global__ __launch_bounds__(256) void prefix2(const float* __restrict__ Sraw,
                                               ushort* __restrict__ SpreB,
                                               const float* __restrict__ Ks,
                                               float* __restrict__ Kpre) {
    const int h = blockIdx.x, eb = blockIdx.y, t = threadIdx.x;
    const int e0 = eb * 512 + t * 2;
    float r0 = 0.f, r1 = 0.f;
    const size_t hb = (size_t)h * NCH * 4096;
    for (int c2 = 0; c2 < NCH; ++c2) {
        const size_t base = hb + (size_t)c2 * 4096 + e0;
        float c0 = Sraw[base], c1 = Sraw[base + 1];
        ushort2 o = make_ushort2(f2b_raw(r0), f2b_raw(r1));
        *(ushort2*)&SpreB[base] = o;
        r0 += c0; r1 += c1;
    }
    if (eb == 0 && t < 64) {
        float rk = 0.f;
        for (int c2 = 0; c2 < NCH; ++c2) {
            const size_t kb2 = ((size_t)h * NCH + c2) * FDM + t;
            float cur = Ks[kb2];
            Kpre[kb2] = rk;
            rk += cur;
        }
    }
}

// ---------------------------------------------------------------------------
// Intra-chunk attention via MFMA.
// ---------------------------------------------------------------------------
__global__ __launch_bounds__(256) void intra2(
    const ushort* __restrict__ fqB, const ushort* __restrict__ fkB,
    const ushort* __restrict__ VTb, const ushort* __restrict__ SpreB,
    const float* __restrict__ Kpre, ushort* __restrict__ Yb) {
    __shared__ __align__(16) ushort fqs[64 * 72];
    __shared__ __align__(16) ushort fks[64 * 72];
    __shared__ __align__(16) ushort VTs[64 * 72];
    __shared__ __align__(16) ushort Sps[64 * 72];
    __shared__ __align__(16) ushort Pms[64 * 72];
    __shared__ float den[64], kpr[64];

    const int c = blockIdx.x, h = blockIdx.y;
    const int t = threadIdx.x, lane = t & 63, wave = t >> 6;
    const int l0 = c * CT;
    const int fr = lane & 15, fo = (lane >> 4) * 8;
    const int g = lane >> 4, cc = lane & 15;

    const size_t qkbase = ((size_t)h * LQ + l0) * FDM;
    const size_t cbase  = ((size_t)h * NCH + c) * 4096;
    for (int it = 0; it < 2; ++it) {
        int e = (it * 256 + t) * 8;
        int row = e >> 6, col = e & 63;
        *(uint4*)&fqs[row * 72 + col] = *(const uint4*)&fqB[qkbase + e];
        *(uint4*)&fks[row * 72 + col] = *(const uint4*)&fkB[qkbase + e];
        *(uint4*)&VTs[row * 72 + col] = *(const uint4*)&VTb[cbase + e];
        *(uint4*)&Sps[row * 72 + col] = *(const uint4*)&SpreB[cbase + e];
    }
    if (t < 64) kpr[t] = Kpre[((size_t)h * NCH + c) * FDM + t];
    __syncthreads();

    // P = fq @ fk^T
    f32x4 accP[4] = {};
#pragma unroll
    for (int kp = 0; kp < 2; ++kp) {
        bf16x8 a = *(const bf16x8*)&fqs[(wave * 16 + fr) * 72 + kp * 32 + fo];
#pragma unroll
        for (int j = 0; j < 4; ++j) {
            bf16x8 b = *(const bf16x8*)&fks[(j * 16 + fr) * 72 + kp * 32 + fo];
            accP[j] = __builtin_amdgcn_mfma_f32_16x16x32_bf16(a, b, accP[j], 0, 0, 0);
        }
    }
#pragma unroll
    for (int j = 0; j < 4; ++j)
#pragma unroll
        for (int r = 0; r < 4; ++r) {
            int l = wave * 16 + g * 4 + r, lp = j * 16 + cc;
            Pms[l * 72 + lp] = (lp <= l) ? f2b_raw(accP[j][r]) : (ushort)0;
        }
    __syncthreads();

    // denominator, 4 threads/row
    {
        const int srow = t >> 2, spart = t & 3;
        float s = 0.f;
#pragma unroll
        for (int i = 0; i < 16; ++i) s += b2f(Pms[srow * 72 + spart * 16 + i]);
#pragma unroll
        for (int i = 0; i < 16; ++i) s += b2f(fqs[srow * 72 + spart * 16 + i]) * kpr[spart * 16 + i];
        s += __shfl_xor(s, 1); s += __shfl_xor(s, 2);
        if (spart == 0) den[srow] = s + EPSV;
    }
    __syncthreads();

    // Y = Pm @ V + fq @ Spre^T
    f32x4 accY[4] = {};
#pragma unroll
    for (int kp = 0; kp < 2; ++kp) {
        bf16x8 a = *(const bf16x8*)&Pms[(wave * 16 + fr) * 72 + kp * 32 + fo];
#pragma unroll
        for (int j = 0; j < 4; ++j) {
            bf16x8 b = *(const bf16x8*)&VTs[(j * 16 + fr) * 72 + kp * 32 + fo];
            accY[j] = __builtin_amdgcn_mfma_f32_16x16x32_bf16(a, b, accY[j], 0, 0, 0);
        }
    }
#pragma unroll
    for (int kp = 0; kp < 2; ++kp) {
        bf16x8 a = *(const bf16x8*)&fqs[(wave * 16 + fr) * 72 + kp * 32 + fo];
#pragma unroll
        for (int j = 0; j < 4; ++j) {
            bf16x8 b = *(const bf16x8*)&Sps[(j * 16 + fr) * 72 + kp * 32 + fo];
            accY[j] = __builtin_amdgcn_mfma_f32_16x16x32_bf16(a, b, accY[j], 0, 0, 0);
        }
    }
#pragma unroll
    for (int r = 0; r < 4; ++r) {
        int l = wave * 16 + g * 4 + r;
        float inv = 1.0f / den[l];
        ushort* yo = Yb + (size_t)(l0 + l) * HID + h * HDM;
#pragma unroll
        for (int j = 0; j < 4; ++j)
            yo[j * 16 + cc] = f2b_raw(accY[j][r] * inv);
    }
}

// ---------------------------------------------------------------------------
extern "C" void kernel_launch(void* const* d_in, const int* in_sizes, int n_in,
                              void* d_out, int out_size, void* d_ws, size_t ws_size,
                              hipStream_t stream) {
    const float* hs  = (const float*)d_in[0];
    const float* Wq  = (const float*)d_in[1];
    const float* Wk  = (const float*)d_in[2];
    const float* Wv  = (const float*)d_in[3];
    const float* Wo  = (const float*)d_in[4];
    const float* Wfq = (const float*)d_in[5];
    const float* Wfk = (const float*)d_in[6];
    float* out = (float*)d_out;

    const size_t SZ = (size_t)LQ * HID;          // 2,097,152
    const size_t WZ = (size_t)HID * HID;         // 4,194,304

    char* w = (char*)d_ws;
    auto aus = [&](size_t n) { ushort* p = (ushort*)w; w += n * sizeof(ushort); return p; };
    auto afl = [&](size_t n) { float*  p = (float*)w;  w += n * sizeof(float);  return p; };

    ushort* hsb   = aus(SZ);
    ushort* wqb   = aus(WZ);
    ushort* wkb   = aus(WZ);
    ushort* wvb   = aus(WZ);
    ushort* wob   = aus(WZ);
    ushort* fqB   = aus(SZ);
    ushort* fkB   = aus(SZ);
    ushort* VTb   = aus(SZ);
    ushort* WfqT  = aus((size_t)NH * 4096);
    ushort* WfkT  = aus((size_t)NH * 4096);
    ushort* SpreB = aus(SZ);
    ushort* Yb    = aus(SZ);
    float*  Sraw  = afl(SZ);
    float*  Ks    = afl((size_t)NH * NCH * FDM);
    float*  Kpre  = afl((size_t)NH * NCH * FDM);

    ConvArgs ca;
    ca.src[0] = hs; ca.dst[0] = hsb; ca.n[0] = (int)SZ;
    ca.src[1] = Wq; ca.dst[1] = wqb; ca.n[1] = (int)WZ;
    ca.src[2] = Wk; ca.dst[2] = wkb; ca.n[2] = (int)WZ;
    ca.src[3] = Wv; ca.dst[3] = wvb; ca.n[3] = (int)WZ;
    ca.src[4] = Wo; ca.dst[4] = wob; ca.n[4] = (int)WZ;
    ca.Wfq = Wfq; ca.Wfk = Wfk; ca.WfqT = WfqT; ca.WfkT = WfkT;
    conv_all<<<dim3((unsigned)(WZ / 1024), 7), 256, 0, stream>>>(ca);

    // 64x128 tiles: grid (16, 16, 3) = 768 blocks = 3 blocks/CU
    gemm_qkv_fm<<<dim3(HID / 128, LQ / 64, 3), 256, 0, stream>>>(
        hsb, wqb, wkb, wvb, WfqT, WfkT, fqB, fkB, VTb);

    chunk_state<<<dim3(NCH, NH), 256, 0, stream>>>(fkB, VTb, Sraw, Ks);

    prefix2<<<dim3(NH, 8), 256, 0, stream>>>(Sraw, SpreB, Ks, Kpre);

    intra2<<<dim3(NCH, NH), 256, 0, stream>>>(fqB, fkB, VTb, SpreB, Kpre, Yb);

    // 64x64 tile: grid 32 x 16 = 512 blocks = 2 blocks/CU
    gemm_one<<<dim3(HID / 64, LQ / 64), 256, 0, stream>>>(Yb, wob, out);
}